// Round 11
// baseline (199.164 us; speedup 1.0000x reference)
//
#include <hip/hip_runtime.h>

typedef float f32x4 __attribute__((ext_vector_type(4)));

#define S0 4096
#define P0 64
#define S1 1024
#define P1 256
#define C  128
#define N_PTS (S0 * P0)

#define SEG_PER_BLK   4                      // 1 segment per wave
#define ASSIGN_BLOCKS (S0 / SEG_PER_BLK)     // 1024
#define TOTAL_BLOCKS  2048                   // 1 slice per block, grid resident
#define NR            ((long)N_PTS * C / 4)  // 8388608 float4
#define NS            ((long)S1 * C / 4)     // 32768 float4
#define SLICE_F4      4096                   // 64 KB slice per block
#define ROT_F4        272                    // +4352 B: flips channel bit 12 -> h1 stream
                                             // decorrelated from pf stream (2^27 is a
                                             // multiple of the interleave period; 4352 isn't)

// ---------------------------------------------------------------------------
// Fused kernel (R4 chassis). Blocks 0..1023 run the proven assign phase
// first (1 wave = 1 segment, shfl reduce, LDS scatter aggregation,
// done-counter finalize). ALL blocks then copy one contiguous 64 KB slice:
//   pass 1: linear read -> o_pf linear write
//   pass 2: read rotated by 272 f4 within the slice (L1/L2 hit -> no extra
//           HBM fetch) -> o_h1 write at rotated addresses, breaking the
//           2^27 channel/bank phase-lock between the two store streams.
// ---------------------------------------------------------------------------
__global__ __launch_bounds__(256) void fused_kernel(
    const float* __restrict__ sp_feat,   // [S1, C]
    const float* __restrict__ pts_feat,  // [S0, P0, C]
    const float* __restrict__ hilb,      // [N, 3]
    const int*   __restrict__ l01,       // [S0]
    const f32x4* __restrict__ raw,       // [NR]
    float*  __restrict__ out_assign,     // [N] (as float)
    f32x4*  __restrict__ o_pf,           // [NR]
    f32x4*  __restrict__ o_h1,           // [NR]
    f32x4*  __restrict__ o_spf,          // [NS]
    float*  __restrict__ out_coord,      // [S1*3]
    float*  __restrict__ ws_sum,         // [S1*3]
    float*  __restrict__ ws_cnt,         // [S1]
    unsigned* __restrict__ ws_done)      // [1]
{
    __shared__ float lsum[4][3][3];   // [wave][cand][xyz]
    __shared__ float lcnt[4][3];
    __shared__ int   last_flag;

    const int tid  = threadIdx.x;
    const int blk  = blockIdx.x;
    const int w    = tid >> 6;
    const int lane = tid & 63;

    if (blk < ASSIGN_BLOCKS) {
        if (tid < 36) ((float*)lsum)[tid] = 0.0f;
        if (tid < 12) ((float*)lcnt)[tid] = 0.0f;
        __syncthreads();

        const int s  = blk * SEG_PER_BLK + w;
        const int sm = (s - 1 < 0) ? 0 : s - 1;
        const int sp = (s + 1 >= S0) ? S0 - 1 : s + 1;
        const int id0 = l01[sm], id1 = l01[s], id2 = l01[sp];

        const int h = lane >> 5;             // which row of the 2-row window
        const int q = (lane & 31) * 4;       // this lane's 4 channels

        const f32x4 c0 = *reinterpret_cast<const f32x4*>(sp_feat + (size_t)id0 * C + q);
        const f32x4 c1 = *reinterpret_cast<const f32x4*>(sp_feat + (size_t)id1 * C + q);
        const f32x4 c2 = *reinterpret_cast<const f32x4*>(sp_feat + (size_t)id2 * C + q);

        const float* segb = pts_feat + (size_t)s * P0 * C;

        #pragma unroll 4
        for (int k = 0; k < 32; ++k) {
            const int row = 2 * k + h;
            f32x4 v = *reinterpret_cast<const f32x4*>(segb + (size_t)row * C + q);
            float p0 = v.x * c0.x + v.y * c0.y + v.z * c0.z + v.w * c0.w;
            float p1 = v.x * c1.x + v.y * c1.y + v.z * c1.z + v.w * c1.w;
            float p2 = v.x * c2.x + v.y * c2.y + v.z * c2.z + v.w * c2.w;
            #pragma unroll
            for (int off = 1; off < 32; off <<= 1) {   // stays within each half
                p0 += __shfl_xor(p0, off);
                p1 += __shfl_xor(p1, off);
                p2 += __shfl_xor(p2, off);
            }
            if ((lane & 31) == 0) {
                int kb = 0; float best = p0;
                if (p1 > best) { best = p1; kb = 1; }
                if (p2 > best) { best = p2; kb = 2; }
                const int gpt = s * P0 + row;
                out_assign[gpt] = (float)(kb == 0 ? id0 : (kb == 1 ? id1 : id2));
                const float* hp = hilb + (size_t)gpt * 3;
                atomicAdd(&lsum[w][kb][0], hp[0]);
                atomicAdd(&lsum[w][kb][1], hp[1]);
                atomicAdd(&lsum[w][kb][2], hp[2]);
                atomicAdd(&lcnt[w][kb], 1.0f);
            }
        }
        __syncthreads();

        if (tid < 12) {
            const int ww = tid / 3, kb = tid % 3;
            if (lcnt[ww][kb] > 0.0f) {
                const int s2 = blk * SEG_PER_BLK + ww;
                int nb = s2 - 1 + kb;
                nb = nb < 0 ? 0 : (nb >= S0 ? S0 - 1 : nb);
                const int id = l01[nb];
                atomicAdd(&ws_cnt[id], lcnt[ww][kb]);
                atomicAdd(&ws_sum[(size_t)id * 3 + 0], lsum[ww][kb][0]);
                atomicAdd(&ws_sum[(size_t)id * 3 + 1], lsum[ww][kb][1]);
                atomicAdd(&ws_sum[(size_t)id * 3 + 2], lsum[ww][kb][2]);
            }
        }
        __syncthreads();   // drains the ws atomics

        // ---- last assign block finalizes the scatter-mean ----
        if (tid == 0) {
            __threadfence();
            last_flag = (atomicAdd(ws_done, 1u) == ASSIGN_BLOCKS - 1) ? 1 : 0;
        }
        __syncthreads();
        if (last_flag) {
            for (int i = tid; i < S1 * 3; i += 256) {
                float sv = atomicAdd(&ws_sum[i], 0.0f);          // device-coherent read
                float cv = atomicAdd(&ws_cnt[i / 3], 0.0f);
                out_coord[i] = sv / fmaxf(cv, 1.0f);
            }
        }
    }

    // ---- copy phase: one 64 KB slice per block ----
    if (blk < 128) {                     // sp_center_feat passthrough
        const long g = (long)blk * 256 + tid;
        o_spf[g] = ((const f32x4*)sp_feat)[g];
    }

    const long base = (long)blk * SLICE_F4;

    // pass 1: linear -> o_pf (slice now hot in L1/L2)
    #pragma unroll
    for (int batch = 0; batch < 2; ++batch) {
        f32x4 v[8];
        #pragma unroll
        for (int t = 0; t < 8; ++t)
            v[t] = raw[base + (long)(batch * 8 + t) * 256 + tid];
        #pragma unroll
        for (int t = 0; t < 8; ++t)
            o_pf[base + (long)(batch * 8 + t) * 256 + tid] = v[t];
    }

    // pass 2: rotated within slice -> o_h1 (reads are cache hits; store
    // stream shifted +4352 B vs pf stream -> different HBM channel phase)
    #pragma unroll
    for (int batch = 0; batch < 2; ++batch) {
        f32x4 u[8];
        int   off2[8];
        #pragma unroll
        for (int t = 0; t < 8; ++t) {
            off2[t] = ((batch * 8 + t) * 256 + tid + ROT_F4) & (SLICE_F4 - 1);
            u[t] = raw[base + off2[t]];
        }
        #pragma unroll
        for (int t = 0; t < 8; ++t)
            o_h1[base + off2[t]] = u[t];
    }
}

extern "C" void kernel_launch(void* const* d_in, const int* in_sizes, int n_in,
                              void* d_out, int out_size, void* d_ws, size_t ws_size,
                              hipStream_t stream) {
    const float* sp_feat  = (const float*)d_in[0];
    // d_in[1] sp_center_coord: unused (only affects tie-order among duplicates)
    const float* raw      = (const float*)d_in[2];
    const float* hilb     = (const float*)d_in[3];
    const float* pts_feat = (const float*)d_in[4];
    // d_in[5] points_coord: unused
    const int*   l01      = (const int*)d_in[6];

    float* out        = (float*)d_out;
    float* out_assign = out;                              // N
    float* out_spfeat = out_assign + N_PTS;               // S1*C
    float* out_coord  = out_spfeat + (size_t)S1 * C;      // S1*3
    float* out_pf     = out_coord + (size_t)S1 * 3;       // S0*P0*C
    float* out_h1     = out_pf + (size_t)S0 * P0 * C;     // S1*P1*C

    float*    ws_sum  = (float*)d_ws;                 // S1*3
    float*    ws_cnt  = ws_sum + (size_t)S1 * 3;      // S1
    unsigned* ws_done = (unsigned*)(ws_cnt + S1);     // 1

    (void)hipMemsetAsync(d_ws, 0, (size_t)(S1 * 3 + S1 + 1) * sizeof(float), stream);

    fused_kernel<<<TOTAL_BLOCKS, 256, 0, stream>>>(
        sp_feat, pts_feat, hilb, l01, (const f32x4*)raw,
        out_assign, (f32x4*)out_pf, (f32x4*)out_h1, (f32x4*)out_spfeat,
        out_coord, ws_sum, ws_cnt, ws_done);
}

// Round 12
// 127.740 us; speedup vs baseline: 1.5591x; 1.5591x over previous
//
#include <hip/hip_runtime.h>

#define S0 4096
#define P0 64
#define S1 1024
#define P1 256
#define C  128
#define N_PTS (S0 * P0)

#define SEG_PER_BLK   4                      // 1 segment per wave
#define ASSIGN_BLOCKS (S0 / SEG_PER_BLK)     // 1024
#define TOTAL_BLOCKS  2048

// ---------------------------------------------------------------------------
// Fused kernel (measured best: 127.2 us).
// Blocks 0..1023: assignment, wave-cooperative. Each wave owns one segment
//   (64 points x 128 ch). The segment is read in 32 coalesced 1-KB steps;
//   step k delivers row 2k to lanes 0-31 and row 2k+1 to lanes 32-63
//   (4 channels per lane). Each half reduces its row's 3 candidate dots via
//   5 intra-half shfl_xor steps. Candidate features live in 12 registers per
//   lane. No barriers in the loop.
// Blocks 1024..2047: copy only. All blocks join the grid-stride copy.
// ---------------------------------------------------------------------------
__global__ __launch_bounds__(256) void fused_kernel(
    const float* __restrict__ sp_feat,   // [S1, C]
    const float* __restrict__ pts_feat,  // [S0, P0, C]
    const float* __restrict__ hilb,      // [N, 3]
    const int*   __restrict__ l01,       // [S0]
    const float4* __restrict__ raw,      // [N*C/4]
    float*  __restrict__ out_assign,     // [N] (as float)
    float4* __restrict__ o_pf,           // [N*C/4]
    float4* __restrict__ o_h1,           // [N*C/4]
    float4* __restrict__ o_spf,          // [S1*C/4]
    float*  __restrict__ ws_sum,         // [S1*3]
    float*  __restrict__ ws_cnt)         // [S1]
{
    __shared__ float lsum[4][3][3];   // [wave][cand][xyz]
    __shared__ float lcnt[4][3];

    const int tid  = threadIdx.x;
    const int blk  = blockIdx.x;
    const int w    = tid >> 6;
    const int lane = tid & 63;

    if (blk < ASSIGN_BLOCKS) {
        if (tid < 36) ((float*)lsum)[tid] = 0.0f;
        if (tid < 12) ((float*)lcnt)[tid] = 0.0f;
        __syncthreads();

        const int s  = blk * SEG_PER_BLK + w;
        const int sm = (s - 1 < 0) ? 0 : s - 1;
        const int sp = (s + 1 >= S0) ? S0 - 1 : s + 1;
        const int id0 = l01[sm], id1 = l01[s], id2 = l01[sp];

        const int h = lane >> 5;             // which row of the 2-row window
        const int q = (lane & 31) * 4;       // this lane's 4 channels

        const float4 c0 = *reinterpret_cast<const float4*>(sp_feat + (size_t)id0 * C + q);
        const float4 c1 = *reinterpret_cast<const float4*>(sp_feat + (size_t)id1 * C + q);
        const float4 c2 = *reinterpret_cast<const float4*>(sp_feat + (size_t)id2 * C + q);

        const float* segb = pts_feat + (size_t)s * P0 * C;

        #pragma unroll 4
        for (int k = 0; k < 32; ++k) {
            const int row = 2 * k + h;
            float4 v = *reinterpret_cast<const float4*>(segb + (size_t)row * C + q);
            float p0 = v.x * c0.x + v.y * c0.y + v.z * c0.z + v.w * c0.w;
            float p1 = v.x * c1.x + v.y * c1.y + v.z * c1.z + v.w * c1.w;
            float p2 = v.x * c2.x + v.y * c2.y + v.z * c2.z + v.w * c2.w;
            #pragma unroll
            for (int off = 1; off < 32; off <<= 1) {   // stays within each half
                p0 += __shfl_xor(p0, off);
                p1 += __shfl_xor(p1, off);
                p2 += __shfl_xor(p2, off);
            }
            if ((lane & 31) == 0) {
                int kb = 0; float best = p0;
                if (p1 > best) { best = p1; kb = 1; }
                if (p2 > best) { best = p2; kb = 2; }
                const int gpt = s * P0 + row;
                out_assign[gpt] = (float)(kb == 0 ? id0 : (kb == 1 ? id1 : id2));
                const float* hp = hilb + (size_t)gpt * 3;
                atomicAdd(&lsum[w][kb][0], hp[0]);
                atomicAdd(&lsum[w][kb][1], hp[1]);
                atomicAdd(&lsum[w][kb][2], hp[2]);
                atomicAdd(&lcnt[w][kb], 1.0f);
            }
        }
        __syncthreads();

        if (tid < 12) {
            const int ww = tid / 3, kb = tid % 3;
            if (lcnt[ww][kb] > 0.0f) {
                const int s2 = blk * SEG_PER_BLK + ww;
                int nb = s2 - 1 + kb;
                nb = nb < 0 ? 0 : (nb >= S0 ? S0 - 1 : nb);
                const int id = l01[nb];
                atomicAdd(&ws_cnt[id], lcnt[ww][kb]);
                atomicAdd(&ws_sum[(size_t)id * 3 + 0], lsum[ww][kb][0]);
                atomicAdd(&ws_sum[(size_t)id * 3 + 1], lsum[ww][kb][1]);
                atomicAdd(&ws_sum[(size_t)id * 3 + 2], lsum[ww][kb][2]);
            }
        }
    }

    // ---- copy phase: all blocks, grid-stride ----
    const long NR = (long)N_PTS * C / 4;   // 8388608
    const long NS = (long)S1 * C / 4;      // 32768
    const long gid    = (long)blk * 256 + tid;
    const long stride = (long)TOTAL_BLOCKS * 256;
    const float4* spf4 = (const float4*)sp_feat;
    for (long i = gid; i < NR; i += stride) {
        float4 v = raw[i];
        o_pf[i] = v;
        o_h1[i] = v;
        if (i < NS) o_spf[i] = spf4[i];
    }
}

// ---------------------------------------------------------------------------
// Finalize scatter-mean (after all atomics).
// ---------------------------------------------------------------------------
__global__ void finalize_kernel(const float* __restrict__ ws_sum,
                                const float* __restrict__ ws_cnt,
                                float* __restrict__ out_coord)
{
    int i = blockIdx.x * blockDim.x + threadIdx.x;
    if (i >= S1 * 3) return;
    out_coord[i] = ws_sum[i] / fmaxf(ws_cnt[i / 3], 1.0f);
}

extern "C" void kernel_launch(void* const* d_in, const int* in_sizes, int n_in,
                              void* d_out, int out_size, void* d_ws, size_t ws_size,
                              hipStream_t stream) {
    const float* sp_feat  = (const float*)d_in[0];
    // d_in[1] sp_center_coord: unused (only affects tie-order among duplicates)
    const float* raw      = (const float*)d_in[2];
    const float* hilb     = (const float*)d_in[3];
    const float* pts_feat = (const float*)d_in[4];
    // d_in[5] points_coord: unused
    const int*   l01      = (const int*)d_in[6];

    float* out        = (float*)d_out;
    float* out_assign = out;                              // N
    float* out_spfeat = out_assign + N_PTS;               // S1*C
    float* out_coord  = out_spfeat + (size_t)S1 * C;      // S1*3
    float* out_pf     = out_coord + (size_t)S1 * 3;       // S0*P0*C
    float* out_h1     = out_pf + (size_t)S0 * P0 * C;     // S1*P1*C

    float* ws_sum = (float*)d_ws;            // S1*3
    float* ws_cnt = ws_sum + (size_t)S1 * 3; // S1

    (void)hipMemsetAsync(d_ws, 0, (size_t)(S1 * 3 + S1) * sizeof(float), stream);

    fused_kernel<<<TOTAL_BLOCKS, 256, 0, stream>>>(
        sp_feat, pts_feat, hilb, l01, (const float4*)raw,
        out_assign, (float4*)out_pf, (float4*)out_h1, (float4*)out_spfeat,
        ws_sum, ws_cnt);

    finalize_kernel<<<(S1 * 3 + 255) / 256, 256, 0, stream>>>(ws_sum, ws_cnt, out_coord);
}